// Round 9
// baseline (595.236 us; speedup 1.0000x reference)
//
#include <hip/hip_runtime.h>

#define NA 96
#define NE 2048
#define NK 16
#define NN 9
#define NF 1728          // 2*NA*NN
#define FEAT 648
#define NP (NA*NA)       // 9216

// Output: real part of (K, F, F) complex64 -> float32, out_size = 47,775,744.
// Written as float4 (4 consecutive real columns).
#define PER_K_RE (NF * (NF / 4))     // 746,496 float4 per k-point
#define SLOTS_RE (NK * PER_K_RE)     // 11,943,936 float4 == 191,102,976 B

// ---- static device scratch (no d_ws dependency; rebuilt every call) -------
__device__ float2 g_phase[NE * NK];      // 256 KB
__device__ int    g_counts[NP];
__device__ int    g_pairoff[NP + 1];
__device__ int    g_paircur[NP];
__device__ int    g_pairidx[NE];

// fill_blocks segment start offsets: stbase[di_idx][dj_idx], dims (1,3,5)
__constant__ int d_stbase[3][3] = {{0, 8, 32}, {72, 96, 168}, {288, 328, 448}};
__constant__ int d_dim[3] = {1, 3, 5};

// Map orbital index i in [0,9) -> (dim index, offset within dim)
__device__ __forceinline__ void orb_decode(int i, int& didx, int& p) {
    if (i == 0)      { didx = 0; p = 0; }
    else if (i < 4)  { didx = 1; p = i - 1; }
    else             { didx = 2; p = i - 4; }
}

// ---------------------------------------------------------------------------
// Kernel 1: phases exp(-i*2pi*shift.k) and zero the pair-count table
// ---------------------------------------------------------------------------
__global__ __launch_bounds__(256) void k_prep(
    const float* __restrict__ kpts,       // [NK, 3]
    const float* __restrict__ shift)      // [NE, 3]
{
    int t = blockIdx.x * blockDim.x + threadIdx.x;
    if (t < NE * NK) {
        int e = t / NK, k = t - e * NK;
        float ang = 6.2831853071795864f *
                    (shift[e * 3 + 0] * kpts[k * 3 + 0] +
                     shift[e * 3 + 1] * kpts[k * 3 + 1] +
                     shift[e * 3 + 2] * kpts[k * 3 + 2]);
        float s, c;
        sincosf(ang, &s, &c);
        g_phase[t] = make_float2(c, -s);  // exp(-i*ang)
    } else if (t < NE * NK + NP) {
        g_counts[t - NE * NK] = 0;
    }
}

// ---------------------------------------------------------------------------
// Kernel 2: count edges per (src,dst) pair
// ---------------------------------------------------------------------------
__global__ __launch_bounds__(256) void k_count(const int* __restrict__ eidx)
{
    int e = blockIdx.x * blockDim.x + threadIdx.x;
    if (e < NE) atomicAdd(&g_counts[eidx[e] * NA + eidx[NE + e]], 1);
}

// ---------------------------------------------------------------------------
// Kernel 3: exclusive scan of 9216 counts (single workgroup)
// ---------------------------------------------------------------------------
__global__ __launch_bounds__(256) void k_scan()
{
    __shared__ int part[256];
    int t = threadIdx.x;
    int base = t * 36;                    // 256*36 == 9216 exactly
    int local[36];
    int sum = 0;
#pragma unroll
    for (int i = 0; i < 36; ++i) { local[i] = g_counts[base + i]; sum += local[i]; }
    part[t] = sum;
    __syncthreads();
    for (int off = 1; off < 256; off <<= 1) {
        int v = (t >= off) ? part[t - off] : 0;
        __syncthreads();
        part[t] += v;
        __syncthreads();
    }
    int run = part[t] - sum;              // exclusive prefix of this chunk
#pragma unroll
    for (int i = 0; i < 36; ++i) {
        g_pairoff[base + i] = run;
        g_paircur[base + i] = run;
        run += local[i];
    }
    if (t == 255) g_pairoff[NP] = run;
}

// ---------------------------------------------------------------------------
// Kernel 4: fill CSR edge lists
// ---------------------------------------------------------------------------
__global__ __launch_bounds__(256) void k_fill(const int* __restrict__ eidx)
{
    int e = blockIdx.x * blockDim.x + threadIdx.x;
    if (e < NE) {
        int pos = atomicAdd(&g_paircur[eidx[e] * NA + eidx[NE + e]], 1);
        g_pairidx[pos] = e;
    }
}

// ---------------------------------------------------------------------------
// Kernel 5: main — real part only. Each thread writes one float4
// (4 consecutive real columns of one output row).
//   Re(out[k,r,c]) = 0.5*( Σ_direct (hx*px - hy*py)
//                        + Σ_herm   (hx'*px - hy'*py)   [Re(conj z) = Re z]
//                        + [a==b] (ons[off1] + ons[off2]) )
// ---------------------------------------------------------------------------
__device__ __forceinline__ float elem_re(
    int k, int aa, int s1, int didx, int p, int di, int c,
    const float* __restrict__ hop_feat, const float* __restrict__ ons_feat)
{
    int s2 = (c >= 864) ? 1 : 0;
    int cc = c - s2 * 864;
    int b  = cc / 9;
    int n2 = cc - b * 9;
    int djdx, q;
    orb_decode(n2, djdx, q);
    int dj   = d_dim[djdx];
    int half = 4 * di * dj;
    // feature offset of block element (ri,ci) and of (ci,ri)
    int off1 = d_stbase[didx][djdx] + ((s1 * 2 + s2) * di + p) * dj + q;
    int off2 = d_stbase[djdx][didx] + ((s2 * 2 + s1) * dj + q) * di + p;

    float a = 0.f;

    // direct: edges src=aa, dst=b -> Re(hop[ri][ci] * phase)
    int p1 = aa * NA + b;
    int o1 = g_pairoff[p1], o1e = g_pairoff[p1 + 1];
    for (int t = o1; t < o1e; ++t) {
        int e = g_pairidx[t];
        const float* row = hop_feat + (size_t)e * FEAT;
        float2 ph = g_phase[e * NK + k];
        a += row[off1] * ph.x - row[off1 + half] * ph.y;
    }
    // hermitian: edges src=b, dst=aa -> Re(conj(hop[ci][ri] * phase))
    int p2 = b * NA + aa;
    int o2 = g_pairoff[p2], o2e = g_pairoff[p2 + 1];
    for (int t = o2; t < o2e; ++t) {
        int e = g_pairidx[t];
        const float* row = hop_feat + (size_t)e * FEAT;
        float2 ph = g_phase[e * NK + k];
        a += row[off2] * ph.x - row[off2 + half] * ph.y;
    }
    // onsite diagonal: Re(ons[ri][ci] + conj(ons[ci][ri]))
    if (aa == b) {
        const float* row = ons_feat + (size_t)aa * FEAT;
        a += row[off1] + row[off2];
    }
    return 0.5f * a;
}

__global__ __launch_bounds__(256) void k_main(
    const float* __restrict__ hop_feat, const float* __restrict__ ons_feat,
    float4* __restrict__ out, int slots)
{
    int stride = gridDim.x * blockDim.x;
    for (int g = blockIdx.x * blockDim.x + threadIdx.x; g < slots; g += stride) {
        unsigned k   = (unsigned)g / PER_K_RE;
        unsigned rem = (unsigned)g - k * PER_K_RE;
        unsigned r   = rem / 432u;          // output row in [0, 1728)
        unsigned cp  = rem - r * 432u;      // float4 index within row
        int c0 = (int)(cp * 4u);            // first of 4 real columns
        int s1 = (r >= 864u) ? 1 : 0;
        int rr = (int)r - s1 * 864;
        int aa = rr / 9;
        int n1 = rr - aa * 9;
        int didx, p;
        orb_decode(n1, didx, p);
        int di = d_dim[didx];

        float v0 = elem_re((int)k, aa, s1, didx, p, di, c0,     hop_feat, ons_feat);
        float v1 = elem_re((int)k, aa, s1, didx, p, di, c0 + 1, hop_feat, ons_feat);
        float v2 = elem_re((int)k, aa, s1, didx, p, di, c0 + 2, hop_feat, ons_feat);
        float v3 = elem_re((int)k, aa, s1, didx, p, di, c0 + 3, hop_feat, ons_feat);
        out[g] = make_float4(v0, v1, v2, v3);
    }
}

// ---------------------------------------------------------------------------
extern "C" void kernel_launch(void* const* d_in, const int* in_sizes, int n_in,
                              void* d_out, int out_size, void* d_ws, size_t ws_size,
                              hipStream_t stream)
{
    const float* hop_feat = (const float*)d_in[0];  // (E, FEAT)
    const float* ons_feat = (const float*)d_in[1];  // (A, FEAT)
    const float* kpts     = (const float*)d_in[2];  // (K, 3)
    const int*   eidx     = (const int*)d_in[3];    // (2, E)
    const float* shift    = (const float*)d_in[4];  // (E, 3)
    (void)in_sizes; (void)n_in; (void)d_ws; (void)ws_size;

    // Evidence (round 8): out_size = 47,775,744 float32 elements — the REAL
    // part of (K,F,F). Cap the write at out_size/4 float4s regardless.
    long long cap = (long long)out_size / 4;
    int slots = (int)(cap < (long long)SLOTS_RE ? cap : (long long)SLOTS_RE);

    const int prep_items = NE * NK + NP;
    k_prep<<<(prep_items + 255) / 256, 256, 0, stream>>>(kpts, shift);
    k_count<<<(NE + 255) / 256, 256, 0, stream>>>(eidx);
    k_scan<<<1, 256, 0, stream>>>();
    k_fill<<<(NE + 255) / 256, 256, 0, stream>>>(eidx);
    k_main<<<2048, 256, 0, stream>>>(hop_feat, ons_feat, (float4*)d_out, slots);
}

// Round 18
// 252.886 us; speedup vs baseline: 2.3538x; 2.3538x over previous
//
#include <hip/hip_runtime.h>

#define NA 96
#define NE 2048
#define NK 16
#define NN 9
#define NF 1728          // 2*NA*NN
#define FEAT 648
#define NP (NA*NA)       // 9216

// Output: real part of (K, F, F) -> float32, out_size = 47,775,744 (evidence r8/r9).
#define PER_K_RE (NF * (NF / 4))     // 746,496 float4 per k-point
#define SLOTS_RE (NK * PER_K_RE)     // 11,943,936 float4 == 191,102,976 B

// ---- static device scratch (no d_ws dependency; rebuilt every call) -------
__device__ float2 g_phase[NE * NK];      // 256 KB, [e][k] contiguous 128B rows
__device__ int    g_counts[NP];
__device__ int    g_pairoff[NP + 1];
__device__ int    g_paircur[NP];
__device__ int    g_pairidx[NE];

// fill_blocks segment start offsets: stbase[di_idx][dj_idx], dims (1,3,5)
__constant__ int d_stbase[3][3] = {{0, 8, 32}, {72, 96, 168}, {288, 328, 448}};
__constant__ int d_dim[3] = {1, 3, 5};

__device__ __forceinline__ void orb_decode(int i, int& didx, int& p) {
    if (i == 0)      { didx = 0; p = 0; }
    else if (i < 4)  { didx = 1; p = i - 1; }
    else             { didx = 2; p = i - 4; }
}

// ---------------------------------------------------------------------------
__global__ __launch_bounds__(256) void k_prep(
    const float* __restrict__ kpts, const float* __restrict__ shift)
{
    int t = blockIdx.x * blockDim.x + threadIdx.x;
    if (t < NE * NK) {
        int e = t / NK, k = t - e * NK;
        float ang = 6.2831853071795864f *
                    (shift[e * 3 + 0] * kpts[k * 3 + 0] +
                     shift[e * 3 + 1] * kpts[k * 3 + 1] +
                     shift[e * 3 + 2] * kpts[k * 3 + 2]);
        float s, c;
        sincosf(ang, &s, &c);
        g_phase[t] = make_float2(c, -s);  // exp(-i*ang)
    } else if (t < NE * NK + NP) {
        g_counts[t - NE * NK] = 0;
    }
}

__global__ __launch_bounds__(256) void k_count(const int* __restrict__ eidx)
{
    int e = blockIdx.x * blockDim.x + threadIdx.x;
    if (e < NE) atomicAdd(&g_counts[eidx[e] * NA + eidx[NE + e]], 1);
}

__global__ __launch_bounds__(256) void k_scan()
{
    __shared__ int part[256];
    int t = threadIdx.x;
    int base = t * 36;                    // 256*36 == 9216 exactly
    int local[36];
    int sum = 0;
#pragma unroll
    for (int i = 0; i < 36; ++i) { local[i] = g_counts[base + i]; sum += local[i]; }
    part[t] = sum;
    __syncthreads();
    for (int off = 1; off < 256; off <<= 1) {
        int v = (t >= off) ? part[t - off] : 0;
        __syncthreads();
        part[t] += v;
        __syncthreads();
    }
    int run = part[t] - sum;
#pragma unroll
    for (int i = 0; i < 36; ++i) {
        g_pairoff[base + i] = run;
        g_paircur[base + i] = run;
        run += local[i];
    }
    if (t == 255) g_pairoff[NP] = run;
}

__global__ __launch_bounds__(256) void k_fill(const int* __restrict__ eidx)
{
    int e = blockIdx.x * blockDim.x + threadIdx.x;
    if (e < NE) {
        int pos = atomicAdd(&g_paircur[eidx[e] * NA + eidx[NE + e]], 1);
        g_pairidx[pos] = e;
    }
}

// ---------------------------------------------------------------------------
// Main: one thread owns one (row, 4-col) float4 for ALL 16 k-points.
// CSR walk + hop reads + column decode happen ONCE; the 128B phase row per
// edge is read as 8 float4s. 16 coalesced float4 stores per thread.
// ---------------------------------------------------------------------------
__global__ __launch_bounds__(256) void k_main(
    const float* __restrict__ hop_feat, const float* __restrict__ ons_feat,
    float4* __restrict__ out, int slots)
{
    int g = blockIdx.x * blockDim.x + threadIdx.x;   // (r, c4) in [0, PER_K_RE)
    if (g >= PER_K_RE) return;

    unsigned r  = (unsigned)g / 432u;     // output row in [0, 1728)
    unsigned cp = (unsigned)g - r * 432u; // float4 index within row
    int c0 = (int)(cp * 4u);
    int s1 = (r >= 864u) ? 1 : 0;
    int rr = (int)r - s1 * 864;
    int aa = rr / 9;
    int n1 = rr - aa * 9;
    int didx, p;
    orb_decode(n1, didx, p);
    int di = d_dim[didx];

    float acc[NK][4];
#pragma unroll
    for (int k = 0; k < NK; ++k) {
#pragma unroll
        for (int j = 0; j < 4; ++j) acc[k][j] = 0.f;
    }

#pragma unroll
    for (int j = 0; j < 4; ++j) {
        int c  = c0 + j;
        int s2 = (c >= 864) ? 1 : 0;
        int cc = c - s2 * 864;
        int b  = cc / 9;
        int n2 = cc - b * 9;
        int djdx, q;
        orb_decode(n2, djdx, q);
        int dj   = d_dim[djdx];
        int half = 4 * di * dj;
        int off1 = d_stbase[didx][djdx] + ((s1 * 2 + s2) * di + p) * dj + q;
        int off2 = d_stbase[djdx][didx] + ((s2 * 2 + s1) * dj + q) * di + p;

        // direct: edges src=aa, dst=b -> Re(hop[ri][ci] * phase_k), all k
        int p1 = aa * NA + b;
        int o1 = g_pairoff[p1], o1e = g_pairoff[p1 + 1];
        for (int t = o1; t < o1e; ++t) {
            int e = g_pairidx[t];
            const float* row = hop_feat + (size_t)e * FEAT;
            float hx = row[off1], hy = row[off1 + half];
            const float4* phr = (const float4*)&g_phase[e * NK];
#pragma unroll
            for (int kk = 0; kk < 8; ++kk) {
                float4 ph2 = phr[kk];                   // (c0,-s0, c1,-s1)
                acc[2 * kk][j]     += hx * ph2.x - hy * ph2.y;
                acc[2 * kk + 1][j] += hx * ph2.z - hy * ph2.w;
            }
        }
        // hermitian: edges src=b, dst=aa -> Re(conj(hop[ci][ri]*phase)) = same form
        int p2 = b * NA + aa;
        int o2 = g_pairoff[p2], o2e = g_pairoff[p2 + 1];
        for (int t = o2; t < o2e; ++t) {
            int e = g_pairidx[t];
            const float* row = hop_feat + (size_t)e * FEAT;
            float hx = row[off2], hy = row[off2 + half];
            const float4* phr = (const float4*)&g_phase[e * NK];
#pragma unroll
            for (int kk = 0; kk < 8; ++kk) {
                float4 ph2 = phr[kk];
                acc[2 * kk][j]     += hx * ph2.x - hy * ph2.y;
                acc[2 * kk + 1][j] += hx * ph2.z - hy * ph2.w;
            }
        }
        // onsite diagonal (same real value added to every k)
        if (aa == b) {
            const float* row = ons_feat + (size_t)aa * FEAT;
            float v = row[off1] + row[off2];
#pragma unroll
            for (int k = 0; k < NK; ++k) acc[k][j] += v;
        }
    }

#pragma unroll
    for (int k = 0; k < NK; ++k) {
        int idx = k * PER_K_RE + g;
        if (idx < slots)
            out[idx] = make_float4(0.5f * acc[k][0], 0.5f * acc[k][1],
                                   0.5f * acc[k][2], 0.5f * acc[k][3]);
    }
}

// ---------------------------------------------------------------------------
extern "C" void kernel_launch(void* const* d_in, const int* in_sizes, int n_in,
                              void* d_out, int out_size, void* d_ws, size_t ws_size,
                              hipStream_t stream)
{
    const float* hop_feat = (const float*)d_in[0];  // (E, FEAT)
    const float* ons_feat = (const float*)d_in[1];  // (A, FEAT)
    const float* kpts     = (const float*)d_in[2];  // (K, 3)
    const int*   eidx     = (const int*)d_in[3];    // (2, E)
    const float* shift    = (const float*)d_in[4];  // (E, 3)
    (void)in_sizes; (void)n_in; (void)d_ws; (void)ws_size;

    long long cap = (long long)out_size / 4;
    int slots = (int)(cap < (long long)SLOTS_RE ? cap : (long long)SLOTS_RE);

    const int prep_items = NE * NK + NP;
    k_prep<<<(prep_items + 255) / 256, 256, 0, stream>>>(kpts, shift);
    k_count<<<(NE + 255) / 256, 256, 0, stream>>>(eidx);
    k_scan<<<1, 256, 0, stream>>>();
    k_fill<<<(NE + 255) / 256, 256, 0, stream>>>(eidx);
    k_main<<<PER_K_RE / 256, 256, 0, stream>>>(hop_feat, ons_feat,
                                               (float4*)d_out, slots);
}